// Round 1
// baseline (1248.797 us; speedup 1.0000x reference)
//
#include <hip/hip_runtime.h>
#include <hip/hip_bf16.h>
#include <cstdint>
#include <cstddef>

typedef __attribute__((ext_vector_type(8))) short short8;
typedef __attribute__((ext_vector_type(4))) float floatx4;
typedef __attribute__((ext_vector_type(4))) unsigned short ushort4_;

#define MFMA16(a, b, c) __builtin_amdgcn_mfma_f32_16x16x32_bf16((a), (b), (c), 0, 0, 0)

__device__ __forceinline__ unsigned short f2bf(float f) {
  __hip_bfloat16 h = __float2bfloat16(f);
  return *reinterpret_cast<unsigned short*>(&h);
}

__device__ __forceinline__ void gl_lds16(const void* g, void* lds) {
  __builtin_amdgcn_global_load_lds(
      (const __attribute__((address_space(1))) void*)g,
      (__attribute__((address_space(3))) void*)lds, 16, 0, 0);
}

// ---------------------------------------------------------------- cast kernel
__global__ void cast_f32_bf16(const float* __restrict__ in, __hip_bfloat16* __restrict__ out) {
  const int i = (blockIdx.x * 256 + threadIdx.x) * 4;
  const float4 v = *reinterpret_cast<const float4*>(in + i);
  ushort4_ o = { f2bf(v.x), f2bf(v.y), f2bf(v.z), f2bf(v.w) };
  *reinterpret_cast<ushort4_*>(out + i) = o;
}

// ---------------------------------------------------------------- GEMM  C = A * B^T + bias
// A: [M][K] bf16 row-major, Bw: [N][K] bf16 row-major (torch Linear weight layout)
// MODE 0: bf16 out, row-major [M][N]
// MODE 1: bf16 out, transposed per-batch: Vt[(b*2048 + n)][t] with m = b*2048 + t
// MODE 2: f32 out, row-major [M][N]
template <int MODE>
__global__ __launch_bounds__(256, 2)
void gemm_bt(const __hip_bfloat16* __restrict__ A, const __hip_bfloat16* __restrict__ Bw,
             const float* __restrict__ bias, void* __restrict__ Cout,
             int M, int N, int K) {
  __shared__ __align__(16) __hip_bfloat16 As[128 * 32];
  __shared__ __align__(16) __hip_bfloat16 Bs[128 * 32];
  const int tid = threadIdx.x;
  const int w = tid >> 6, lane = tid & 63;
  const int g = lane >> 4, c16 = lane & 15;
  const int nbn = N >> 7;
  const int bm = blockIdx.x / nbn, bn = blockIdx.x % nbn;
  const int wr = w >> 1, wc = w & 1;

  floatx4 acc[4][4] = {};

  const int srow = lane >> 2;        // row within 16-row chunk
  const int sseg = (lane & 3) * 8;   // bf16-element offset within a 32-elem row
  const int nkt = K >> 5;
  for (int kt = 0; kt < nkt; ++kt) {
    const int kb = kt * 32;
#pragma unroll
    for (int i = 0; i < 2; ++i) {
      const int cidx = w + i * 4;               // 8 chunks of 16 rows
      const int row = cidx * 16 + srow;
      gl_lds16(A + (size_t)(bm * 128 + row) * K + kb + sseg, As + cidx * 512);
      gl_lds16(Bw + (size_t)(bn * 128 + row) * K + kb + sseg, Bs + cidx * 512);
    }
    __syncthreads();   // drains vmcnt -> staged tiles visible
    short8 af[4], bf[4];
#pragma unroll
    for (int m = 0; m < 4; ++m)
      af[m] = *reinterpret_cast<const short8*>(As + (wr * 64 + m * 16 + c16) * 32 + g * 8);
#pragma unroll
    for (int n = 0; n < 4; ++n)
      bf[n] = *reinterpret_cast<const short8*>(Bs + (wc * 64 + n * 16 + c16) * 32 + g * 8);
#pragma unroll
    for (int m = 0; m < 4; ++m)
#pragma unroll
      for (int n = 0; n < 4; ++n)
        acc[m][n] = MFMA16(af[m], bf[n], acc[m][n]);
    __syncthreads();
  }

#pragma unroll
  for (int n = 0; n < 4; ++n) {
    const int colg = bn * 128 + wc * 64 + n * 16 + c16;
    const float bv = bias[colg];
#pragma unroll
    for (int m = 0; m < 4; ++m) {
      const int rowg = bm * 128 + wr * 64 + m * 16 + g * 4;
      if (MODE == 0) {
        __hip_bfloat16* C = (__hip_bfloat16*)Cout;
#pragma unroll
        for (int j = 0; j < 4; ++j)
          C[(size_t)(rowg + j) * N + colg] = __float2bfloat16(acc[m][n][j] + bv);
      } else if (MODE == 1) {
        __hip_bfloat16* C = (__hip_bfloat16*)Cout;
        const int bb = rowg >> 11, t0 = rowg & 2047;   // batch, token (tiles never straddle)
        ushort4_ pk = { f2bf(acc[m][n][0] + bv), f2bf(acc[m][n][1] + bv),
                        f2bf(acc[m][n][2] + bv), f2bf(acc[m][n][3] + bv) };
        *reinterpret_cast<ushort4_*>(C + ((size_t)bb * 2048 + colg) * 2048 + t0) = pk;
      } else {
        float* C = (float*)Cout;
#pragma unroll
        for (int j = 0; j < 4; ++j)
          C[(size_t)(rowg + j) * N + colg] = acc[m][n][j] + bv;
      }
    }
  }
}

// ---------------------------------------------------------------- flash attention (causal)
// Q, K: [B*T][2048] bf16 (head h at column h*128).  Vt: [(b*16+h)*128 + d][t] bf16.
// ctx out: [B*T][2048] bf16.
__global__ __launch_bounds__(256, 2)
void attn_fwd(const __hip_bfloat16* __restrict__ Q, const __hip_bfloat16* __restrict__ K,
              const __hip_bfloat16* __restrict__ Vt, __hip_bfloat16* __restrict__ ctx) {
  constexpr int T = 2048, C = 2048, D = 128;
  const int tid = threadIdx.x;
  const int w = tid >> 6, lane = tid & 63;
  const int g = lane >> 4, c16 = lane & 15;
  const int bh = blockIdx.x >> 5, qt = blockIdx.x & 31;   // 64 head-instances x 32 q-tiles
  const int b = bh >> 4, h = bh & 15;
  const int qw = qt * 64 + w * 16;                        // this wave's q-row base

  const __hip_bfloat16* Qh = Q + (size_t)b * T * C + h * D;
  const __hip_bfloat16* Kh = K + (size_t)b * T * C + h * D;
  const __hip_bfloat16* Vh = Vt + (size_t)bh * D * T;

  short8 qf[4];
#pragma unroll
  for (int kk = 0; kk < 4; ++kk)
    qf[kk] = *reinterpret_cast<const short8*>(Qh + (size_t)(qw + c16) * C + kk * 32 + g * 8);

  floatx4 acc[8] = {};
  float mrow[4] = {-INFINITY, -INFINITY, -INFINITY, -INFINITY};
  float lrow[4] = {0.f, 0.f, 0.f, 0.f};

  __shared__ __align__(16) __hip_bfloat16 Plds[4][16 * 32];  // per-wave private P buffer
  __hip_bfloat16* Pw = Plds[w];
  const float scale = 0.08838834764831845f;  // 1/sqrt(128)

  const int nkt = (qw >> 5) + 1;             // causal: k-tiles of 32 up to the diagonal
  for (int kt = 0; kt < nkt; ++kt) {
    const int kb = kt * 32;
    floatx4 s0 = {}, s1 = {};
#pragma unroll
    for (int kk = 0; kk < 4; ++kk) {
      short8 k0 = *reinterpret_cast<const short8*>(Kh + (size_t)(kb + c16) * C + kk * 32 + g * 8);
      short8 k1 = *reinterpret_cast<const short8*>(Kh + (size_t)(kb + 16 + c16) * C + kk * 32 + g * 8);
      s0 = MFMA16(qf[kk], k0, s0);
      s1 = MFMA16(qf[kk], k1, s1);
    }
    const bool diag = (kt == nkt - 1);
    float p0[4], p1[4], sc[4];
#pragma unroll
    for (int j = 0; j < 4; ++j) {
      float a0 = s0[j] * scale, a1 = s1[j] * scale;
      if (diag) {
        const int qrow = qw + g * 4 + j;
        if (kb + c16 > qrow) a0 = -INFINITY;        // col = lane&15
        if (kb + 16 + c16 > qrow) a1 = -INFINITY;
      }
      float v = fmaxf(a0, a1);
#pragma unroll
      for (int o = 1; o < 16; o <<= 1) v = fmaxf(v, __shfl_xor(v, o));
      const float mn = fmaxf(mrow[j], v);
      sc[j] = __expf(mrow[j] - mn);
      p0[j] = __expf(a0 - mn);
      p1[j] = __expf(a1 - mn);
      float rs = p0[j] + p1[j];
#pragma unroll
      for (int o = 1; o < 16; o <<= 1) rs += __shfl_xor(rs, o);
      lrow[j] = lrow[j] * sc[j] + rs;
      mrow[j] = mn;
    }
#pragma unroll
    for (int dt = 0; dt < 8; ++dt)
#pragma unroll
      for (int j = 0; j < 4; ++j) acc[dt][j] *= sc[j];
    // C-frag layout (row=g*4+j, col=c16) -> A-frag layout via per-wave LDS (DS is in-order per wave)
#pragma unroll
    for (int j = 0; j < 4; ++j) {
      Pw[(g * 4 + j) * 32 + c16] = __float2bfloat16(p0[j]);
      Pw[(g * 4 + j) * 32 + 16 + c16] = __float2bfloat16(p1[j]);
    }
    short8 ap = *reinterpret_cast<const short8*>(Pw + c16 * 32 + g * 8);
#pragma unroll
    for (int dt = 0; dt < 8; ++dt) {
      short8 bv = *reinterpret_cast<const short8*>(Vh + (size_t)(dt * 16 + c16) * T + kb + g * 8);
      acc[dt] = MFMA16(ap, bv, acc[dt]);
    }
  }

  float inv[4];
#pragma unroll
  for (int j = 0; j < 4; ++j) inv[j] = 1.0f / lrow[j];
#pragma unroll
  for (int dt = 0; dt < 8; ++dt)
#pragma unroll
    for (int j = 0; j < 4; ++j)
      ctx[((size_t)b * T + qw + g * 4 + j) * C + h * D + dt * 16 + c16] =
          __float2bfloat16(acc[dt][j] * inv[j]);
}

// ---------------------------------------------------------------- launch
extern "C" void kernel_launch(void* const* d_in, const int* in_sizes, int n_in,
                              void* d_out, int out_size, void* d_ws, size_t ws_size,
                              hipStream_t stream) {
  const float* x  = (const float*)d_in[0];
  const float* Wq = (const float*)d_in[1];
  const float* bq = (const float*)d_in[2];
  const float* Wk = (const float*)d_in[3];
  const float* bk = (const float*)d_in[4];
  const float* Wv = (const float*)d_in[5];
  const float* bv = (const float*)d_in[6];
  const float* Wo = (const float*)d_in[7];
  const float* bo = (const float*)d_in[8];

  const int M = 8192, N = 2048, K = 2048;
  const size_t MB = 1u << 20;
  char* ws = (char*)d_ws;
  // layout: xb 32M | wq 8M | wk 8M | wv 8M | wo 8M | Q 32M | K 32M | Vt 32M  = 160 MiB
  __hip_bfloat16* xb  = (__hip_bfloat16*)(ws);
  __hip_bfloat16* wqb = (__hip_bfloat16*)(ws + 32 * MB);
  __hip_bfloat16* wkb = (__hip_bfloat16*)(ws + 40 * MB);
  __hip_bfloat16* wvb = (__hip_bfloat16*)(ws + 48 * MB);
  __hip_bfloat16* wob = (__hip_bfloat16*)(ws + 56 * MB);
  __hip_bfloat16* Qb  = (__hip_bfloat16*)(ws + 64 * MB);
  __hip_bfloat16* Kb  = (__hip_bfloat16*)(ws + 96 * MB);
  __hip_bfloat16* Vtb = (__hip_bfloat16*)(ws + 128 * MB);
  if (ws_size < 160 * MB) return;  // workspace too small -> fail loudly (poison stays)

  cast_f32_bf16<<<(M * N) / 1024, 256, 0, stream>>>(x, xb);
  cast_f32_bf16<<<(N * K) / 1024, 256, 0, stream>>>(Wq, wqb);
  cast_f32_bf16<<<(N * K) / 1024, 256, 0, stream>>>(Wk, wkb);
  cast_f32_bf16<<<(N * K) / 1024, 256, 0, stream>>>(Wv, wvb);
  cast_f32_bf16<<<(N * K) / 1024, 256, 0, stream>>>(Wo, wob);

  const dim3 gg((M / 128) * (N / 128));
  gemm_bt<0><<<gg, 256, 0, stream>>>(xb, wqb, bq, Qb, M, N, K);
  gemm_bt<0><<<gg, 256, 0, stream>>>(xb, wkb, bk, Kb, M, N, K);
  gemm_bt<1><<<gg, 256, 0, stream>>>(xb, wvb, bv, Vtb, M, N, K);

  attn_fwd<<<64 * 32, 256, 0, stream>>>(Qb, Kb, Vtb, xb);  // ctx overwrites xb (x is dead)

  gemm_bt<2><<<gg, 256, 0, stream>>>(xb, wob, bo, d_out, M, N, K);
}

// Round 2
// 597.939 us; speedup vs baseline: 2.0885x; 2.0885x over previous
//
#include <hip/hip_runtime.h>
#include <hip/hip_bf16.h>
#include <cstdint>
#include <cstddef>

typedef __attribute__((ext_vector_type(8))) short short8;
typedef __attribute__((ext_vector_type(4))) float floatx4;
typedef __attribute__((ext_vector_type(4))) unsigned short ushort4_;

#define MFMA16(a, b, c) __builtin_amdgcn_mfma_f32_16x16x32_bf16((a), (b), (c), 0, 0, 0)

__device__ __forceinline__ unsigned short f2bf(float f) {
  __hip_bfloat16 h = __float2bfloat16(f);
  return *reinterpret_cast<unsigned short*>(&h);
}

__device__ __forceinline__ void gl_lds16(const void* g, void* lds) {
  __builtin_amdgcn_global_load_lds(
      (const __attribute__((address_space(1))) void*)g,
      (__attribute__((address_space(3))) void*)lds, 16, 0, 0);
}

// ---------------------------------------------------------------- cast kernel
__global__ void cast_f32_bf16(const float* __restrict__ in, __hip_bfloat16* __restrict__ out) {
  const int i = (blockIdx.x * 256 + threadIdx.x) * 4;
  const float4 v = *reinterpret_cast<const float4*>(in + i);
  ushort4_ o = { f2bf(v.x), f2bf(v.y), f2bf(v.z), f2bf(v.w) };
  *reinterpret_cast<ushort4_*>(out + i) = o;
}

// ---------------------------------------------------------------- GEMM  C = A * B^T + bias
// A: [M][K] bf16 row-major, Bw: [N][K] bf16 row-major (torch Linear weight layout)
// MODE 0: bf16 out, row-major [M][N]
// MODE 1: bf16 out, transposed per-batch: Vt[(b*2048 + n)][t] with m = b*2048 + t
// MODE 2: f32 out, row-major [M][N]
template <int MODE>
__global__ __launch_bounds__(256, 2)
void gemm_bt(const __hip_bfloat16* __restrict__ A, const __hip_bfloat16* __restrict__ Bw,
             const float* __restrict__ bias, void* __restrict__ Cout,
             int M, int N, int K) {
  __shared__ __align__(16) __hip_bfloat16 As[128 * 32];
  __shared__ __align__(16) __hip_bfloat16 Bs[128 * 32];
  const int tid = threadIdx.x;
  const int w = tid >> 6, lane = tid & 63;
  const int g = lane >> 4, c16 = lane & 15;
  const int nbn = N >> 7;
  const int bm = blockIdx.x / nbn, bn = blockIdx.x % nbn;
  const int wr = w >> 1, wc = w & 1;

  floatx4 acc[4][4] = {};

  const int srow = lane >> 2;        // row within 16-row chunk
  const int sseg = (lane & 3) * 8;   // bf16-element offset within a 32-elem row
  const int nkt = K >> 5;
  for (int kt = 0; kt < nkt; ++kt) {
    const int kb = kt * 32;
#pragma unroll
    for (int i = 0; i < 2; ++i) {
      const int cidx = w + i * 4;               // 8 chunks of 16 rows
      const int row = cidx * 16 + srow;
      gl_lds16(A + (size_t)(bm * 128 + row) * K + kb + sseg, As + cidx * 512);
      gl_lds16(Bw + (size_t)(bn * 128 + row) * K + kb + sseg, Bs + cidx * 512);
    }
    __syncthreads();   // drains vmcnt -> staged tiles visible
    short8 af[4], bf[4];
#pragma unroll
    for (int m = 0; m < 4; ++m)
      af[m] = *reinterpret_cast<const short8*>(As + (wr * 64 + m * 16 + c16) * 32 + g * 8);
#pragma unroll
    for (int n = 0; n < 4; ++n)
      bf[n] = *reinterpret_cast<const short8*>(Bs + (wc * 64 + n * 16 + c16) * 32 + g * 8);
#pragma unroll
    for (int m = 0; m < 4; ++m)
#pragma unroll
      for (int n = 0; n < 4; ++n)
        acc[m][n] = MFMA16(af[m], bf[n], acc[m][n]);
    __syncthreads();
  }

#pragma unroll
  for (int n = 0; n < 4; ++n) {
    const int colg = bn * 128 + wc * 64 + n * 16 + c16;
    const float bv = bias[colg];
#pragma unroll
    for (int m = 0; m < 4; ++m) {
      const int rowg = bm * 128 + wr * 64 + m * 16 + g * 4;
      if (MODE == 0) {
        __hip_bfloat16* C = (__hip_bfloat16*)Cout;
#pragma unroll
        for (int j = 0; j < 4; ++j)
          C[(size_t)(rowg + j) * N + colg] = __float2bfloat16(acc[m][n][j] + bv);
      } else if (MODE == 1) {
        __hip_bfloat16* C = (__hip_bfloat16*)Cout;
        const int bb = rowg >> 11, t0 = rowg & 2047;   // batch, token (tiles never straddle)
        ushort4_ pk = { f2bf(acc[m][n][0] + bv), f2bf(acc[m][n][1] + bv),
                        f2bf(acc[m][n][2] + bv), f2bf(acc[m][n][3] + bv) };
        *reinterpret_cast<ushort4_*>(C + ((size_t)bb * 2048 + colg) * 2048 + t0) = pk;
      } else {
        float* C = (float*)Cout;
#pragma unroll
        for (int j = 0; j < 4; ++j)
          C[(size_t)(rowg + j) * N + colg] = acc[m][n][j] + bv;
      }
    }
  }
}

// ---------------------------------------------------------------- flash attention v2 (causal)
// Q, K: [B*T][2048] bf16 (head h at column h*128).  Vt: [(b*16+h)*128 + d][t] bf16.
// ctx out: [B*T][2048] bf16.
// Block = 4 waves, QBLK=128 (32 q-rows/wave), KBLK=64, K/V staged in padded LDS.
__global__ __launch_bounds__(256, 2)
void attn_fwd2(const __hip_bfloat16* __restrict__ Q, const __hip_bfloat16* __restrict__ K,
               const __hip_bfloat16* __restrict__ Vt, __hip_bfloat16* __restrict__ ctx) {
  constexpr int T = 2048, C = 2048, D = 128;
  __shared__ __align__(16) __hip_bfloat16 Ks[64][136];    // +8 pad: 272B stride == 4 mod 32 words
  __shared__ __align__(16) __hip_bfloat16 Vs[128][72];    // +8 pad: 144B stride
  __shared__ __align__(16) __hip_bfloat16 Pl[4][32][72];  // per-wave P re-layout buffer

  const int tid = threadIdx.x;
  const int w = tid >> 6, lane = tid & 63;
  const int g = lane >> 4, c16 = lane & 15;

  // XCD-chunked swizzle (grid=1024, 8 XCDs) + heavy q-blocks first within each head
  const int bid = blockIdx.x;
  const int swz = (bid & 7) * 128 + (bid >> 3);
  const int bh = swz >> 4, qb = 15 - (swz & 15);
  const int b = bh >> 4, h = bh & 15;
  const int wq = qb * 128 + w * 32;          // wave's first q row

  const __hip_bfloat16* Qh = Q + (size_t)b * T * C + h * D;
  const __hip_bfloat16* Kh = K + (size_t)b * T * C + h * D;
  const __hip_bfloat16* Vh = Vt + (size_t)bh * D * T;

  short8 qf[2][4];
#pragma unroll
  for (int m = 0; m < 2; ++m)
#pragma unroll
    for (int kk = 0; kk < 4; ++kk)
      qf[m][kk] = *reinterpret_cast<const short8*>(Qh + (size_t)(wq + m * 16 + c16) * C + kk * 32 + g * 8);

  floatx4 acc[2][8] = {};
  float mrow[2][4], lrow[2][4];
#pragma unroll
  for (int m = 0; m < 2; ++m)
#pragma unroll
    for (int j = 0; j < 4; ++j) { mrow[m][j] = -INFINITY; lrow[m][j] = 0.f; }

  const float scale = 0.08838834764831845f;  // 1/sqrt(128)
  const int krow = tid >> 4, kcol = (tid & 15) * 8;   // K staging: 16 rows/pass
  const int vrow = tid >> 3, vcol = (tid & 7) * 8;    // V staging: 32 rows/pass

  const int nkt = qb * 2 + 2;
  for (int kt = 0; kt < nkt; ++kt) {
    const int kb = kt * 64;
    // ---- stage K[kb..kb+63][0..127] and Vt[0..127][kb..kb+63]: global -> reg
    short8 kr[4], vr[4];
#pragma unroll
    for (int p = 0; p < 4; ++p)
      kr[p] = *reinterpret_cast<const short8*>(Kh + (size_t)(kb + p * 16 + krow) * C + kcol);
#pragma unroll
    for (int p = 0; p < 4; ++p)
      vr[p] = *reinterpret_cast<const short8*>(Vh + (size_t)(p * 32 + vrow) * T + kb + vcol);
    __syncthreads();   // prior tile fully consumed
#pragma unroll
    for (int p = 0; p < 4; ++p)
      *reinterpret_cast<short8*>(&Ks[p * 16 + krow][kcol]) = kr[p];
#pragma unroll
    for (int p = 0; p < 4; ++p)
      *reinterpret_cast<short8*>(&Vs[p * 32 + vrow][vcol]) = vr[p];
    __syncthreads();   // staged tile visible

    if (kb <= wq + 31) {                     // wave-uniform: any unmasked work?
      const bool needmask = (kb + 63 > wq);
      // ---- QK^T: S[32 q][64 k]
      floatx4 s[2][4] = {};
#pragma unroll
      for (int n = 0; n < 4; ++n)
#pragma unroll
        for (int kk = 0; kk < 4; ++kk) {
          short8 kf = *reinterpret_cast<const short8*>(&Ks[n * 16 + c16][kk * 32 + g * 8]);
          s[0][n] = MFMA16(qf[0][kk], kf, s[0][n]);
          s[1][n] = MFMA16(qf[1][kk], kf, s[1][n]);
        }
      // ---- online softmax (rows live in 16-lane groups; row=g*4+j, col=n*16+c16)
      __hip_bfloat16 (*Pq)[72] = Pl[w];
#pragma unroll
      for (int m = 0; m < 2; ++m)
#pragma unroll
        for (int j = 0; j < 4; ++j) {
          const int qrow = wq + m * 16 + g * 4 + j;
          float a[4];
#pragma unroll
          for (int n = 0; n < 4; ++n) {
            a[n] = s[m][n][j] * scale;
            if (needmask && (kb + n * 16 + c16 > qrow)) a[n] = -INFINITY;
          }
          float v = fmaxf(fmaxf(a[0], a[1]), fmaxf(a[2], a[3]));
#pragma unroll
          for (int o = 1; o < 16; o <<= 1) v = fmaxf(v, __shfl_xor(v, o));
          const float mn = fmaxf(mrow[m][j], v);
          const float sc = __expf(mrow[m][j] - mn);
          float rs = 0.f;
#pragma unroll
          for (int n = 0; n < 4; ++n) { a[n] = __expf(a[n] - mn); rs += a[n]; }
#pragma unroll
          for (int o = 1; o < 16; o <<= 1) rs += __shfl_xor(rs, o);
          lrow[m][j] = lrow[m][j] * sc + rs;
          mrow[m][j] = mn;
#pragma unroll
          for (int dt = 0; dt < 8; ++dt) acc[m][dt][j] *= sc;
#pragma unroll
          for (int n = 0; n < 4; ++n)
            Pq[m * 16 + g * 4 + j][n * 16 + c16] = __float2bfloat16(a[n]);
        }
      // ---- PV: acc[m][dt] += P[32][64] * V[64][dt*16..]
      short8 ap[2][2];
#pragma unroll
      for (int m = 0; m < 2; ++m)
#pragma unroll
        for (int ks = 0; ks < 2; ++ks)
          ap[m][ks] = *reinterpret_cast<const short8*>(&Pq[m * 16 + c16][ks * 32 + g * 8]);
#pragma unroll
      for (int dt = 0; dt < 8; ++dt)
#pragma unroll
        for (int ks = 0; ks < 2; ++ks) {
          short8 vf = *reinterpret_cast<const short8*>(&Vs[dt * 16 + c16][ks * 32 + g * 8]);
          acc[0][dt] = MFMA16(ap[0][ks], vf, acc[0][dt]);
          acc[1][dt] = MFMA16(ap[1][ks], vf, acc[1][dt]);
        }
    }
  }

  // ---- epilogue
#pragma unroll
  for (int m = 0; m < 2; ++m)
#pragma unroll
    for (int j = 0; j < 4; ++j) {
      const float inv = 1.0f / lrow[m][j];
      const size_t row = (size_t)b * T + wq + m * 16 + g * 4 + j;
#pragma unroll
      for (int dt = 0; dt < 8; ++dt)
        ctx[row * C + h * D + dt * 16 + c16] = __float2bfloat16(acc[m][dt][j] * inv);
    }
}

// ---------------------------------------------------------------- launch
extern "C" void kernel_launch(void* const* d_in, const int* in_sizes, int n_in,
                              void* d_out, int out_size, void* d_ws, size_t ws_size,
                              hipStream_t stream) {
  const float* x  = (const float*)d_in[0];
  const float* Wq = (const float*)d_in[1];
  const float* bq = (const float*)d_in[2];
  const float* Wk = (const float*)d_in[3];
  const float* bk = (const float*)d_in[4];
  const float* Wv = (const float*)d_in[5];
  const float* bv = (const float*)d_in[6];
  const float* Wo = (const float*)d_in[7];
  const float* bo = (const float*)d_in[8];

  const int M = 8192, N = 2048, K = 2048;
  const size_t MB = 1u << 20;
  char* ws = (char*)d_ws;
  // layout: xb 32M | wq 8M | wk 8M | wv 8M | wo 8M | Q 32M | K 32M | Vt 32M  = 160 MiB
  __hip_bfloat16* xb  = (__hip_bfloat16*)(ws);
  __hip_bfloat16* wqb = (__hip_bfloat16*)(ws + 32 * MB);
  __hip_bfloat16* wkb = (__hip_bfloat16*)(ws + 40 * MB);
  __hip_bfloat16* wvb = (__hip_bfloat16*)(ws + 48 * MB);
  __hip_bfloat16* wob = (__hip_bfloat16*)(ws + 56 * MB);
  __hip_bfloat16* Qb  = (__hip_bfloat16*)(ws + 64 * MB);
  __hip_bfloat16* Kb  = (__hip_bfloat16*)(ws + 96 * MB);
  __hip_bfloat16* Vtb = (__hip_bfloat16*)(ws + 128 * MB);
  if (ws_size < 160 * MB) return;  // workspace too small -> fail loudly (poison stays)

  cast_f32_bf16<<<(M * N) / 1024, 256, 0, stream>>>(x, xb);
  cast_f32_bf16<<<(N * K) / 1024, 256, 0, stream>>>(Wq, wqb);
  cast_f32_bf16<<<(N * K) / 1024, 256, 0, stream>>>(Wk, wkb);
  cast_f32_bf16<<<(N * K) / 1024, 256, 0, stream>>>(Wv, wvb);
  cast_f32_bf16<<<(N * K) / 1024, 256, 0, stream>>>(Wo, wob);

  const dim3 gg((M / 128) * (N / 128));
  gemm_bt<0><<<gg, 256, 0, stream>>>(xb, wqb, bq, Qb, M, N, K);
  gemm_bt<0><<<gg, 256, 0, stream>>>(xb, wkb, bk, Kb, M, N, K);
  gemm_bt<1><<<gg, 256, 0, stream>>>(xb, wvb, bv, Vtb, M, N, K);

  attn_fwd2<<<64 * 16, 256, 0, stream>>>(Qb, Kb, Vtb, xb);  // ctx overwrites xb (x is dead)

  gemm_bt<2><<<gg, 256, 0, stream>>>(xb, wob, bo, d_out, M, N, K);
}